// Round 13
// baseline (40.509 us; speedup 1.0000x reference)
//
#include <hip/hip_runtime.h>

// EnergyPool2d: N=16, C=64, H=W=128, 3x3 windows stride 1 -> Ho=Wo=126.
// +1 at first-argmax flat index, -1 at first-argmin flat index per window.
//
// R13: pure-streaming GATHER — no LDS, no atomics, no barriers.
// count+(i,j) = #{windows w containing (i,j) : first-argmax(w) == (i,j)}
// Separable: h-stat per (row, wj) = first-occurrence 1x3 argmax (max3 +
// backward equality select). (i,j) wins window (wi,wj) iff hA[i][wj]==j
// and row i wins the vertical first-occurrence contest over rows wi..wi+2:
//   vr(i,wj) = (v0>vm2 & v0>vm1) + (v0>vm1 & v0>=vp1) + (v0>=vp1 & v0>=vp2)
// (strict vs earlier rows, non-strict vs later rows = row-major tie-break).
// Invalid rows (outside [0,127]) get sentinel M=+INF / m=-INF, which kills
// every window containing them with zero extra gating. Invalid wj (outside
// [0,125]) are handled by zeroing vr. Thread owns 16 rows x 4 cols and
// rolls a 5-row x 6-wj h-stat window in registers (fully unrolled macros,
// all indices compile-time -> no scratch).

#define WW 128
#define PLANE (128 * 128)
#define NPLANES (16 * 64)
#define BLOCK 256
#define INFP __builtin_inff()

// Compute h-stats (both sides) for absolute row rr into rolling slot `slot`.
// cz_[z] = input at column (c0 - 2 + z), z = 0..7. Garbage at edges is
// gated downstream (lv/rv on vr, row sentinel here).
#define HSTAT(slot, rr)                                                      \
  {                                                                          \
    const int r_ = (rr);                                                     \
    const bool rvalid_ = (r_ >= 0) && (r_ <= 127);                           \
    const int rc_ = r_ < 0 ? 0 : (r_ > 127 ? 127 : r_);                      \
    const float* row_ = xp + rc_ * WW;                                       \
    const float4 f0_ = *(const float4*)(row_ + bc0);                         \
    const float4 f1_ = *(const float4*)(row_ + c0);                          \
    const float4 f2_ = *(const float4*)(row_ + bc2);                         \
    const float cz_[8] = {f0_.z, f0_.w, f1_.x, f1_.y,                        \
                          f1_.z, f1_.w, f2_.x, f2_.y};                       \
    int apk_ = 0, amk_ = 0;                                                  \
    _Pragma("unroll")                                                        \
    for (int w_ = 0; w_ < 6; ++w_) {                                         \
      const float v0_ = cz_[w_], v1_ = cz_[w_ + 1], v2_ = cz_[w_ + 2];       \
      float Mv_ = fmaxf(fmaxf(v0_, v1_), v2_);                               \
      int A_ = 2;                                                            \
      if (v1_ == Mv_) A_ = 1;                                                \
      if (v0_ == Mv_) A_ = 0;                                                \
      float mv_ = fminf(fminf(v0_, v1_), v2_);                               \
      int a_ = 2;                                                            \
      if (v1_ == mv_) a_ = 1;                                                \
      if (v0_ == mv_) a_ = 0;                                                \
      if (!rvalid_) { Mv_ = INFP; mv_ = -INFP; }                             \
      M[slot][w_] = Mv_;                                                     \
      m[slot][w_] = mv_;                                                     \
      apk_ |= A_ << (2 * w_);                                                \
      amk_ |= a_ << (2 * w_);                                                \
    }                                                                        \
    Ap[slot] = apk_;                                                         \
    ap[slot] = amk_;                                                         \
  }

// Produce output row i = r0 + s. Slot layout: row (r0+s-2+t) lives in slot
// (s+t)%5, t=0..4. First bring in row r0+s+2, then vertical counts + cells.
#define STEPROW(s)                                                           \
  {                                                                          \
    HSTAT((s + 4) % 5, r0 + (s) + 2);                                        \
    int vrM_[6], vrm_[6];                                                    \
    _Pragma("unroll")                                                        \
    for (int w_ = 0; w_ < 6; ++w_) {                                         \
      const float x0_ = M[(s + 2) % 5][w_];                                  \
      const float xm2_ = M[(s) % 5][w_], xm1_ = M[(s + 1) % 5][w_];          \
      const float xp1_ = M[(s + 3) % 5][w_], xp2_ = M[(s + 4) % 5][w_];      \
      const int c1_ = x0_ > xm2_, c2_ = x0_ > xm1_;                          \
      const int c3_ = x0_ >= xp1_, c4_ = x0_ >= xp2_;                        \
      int v_ = (c1_ & c2_) + (c2_ & c3_) + (c3_ & c4_);                      \
      const float y0_ = m[(s + 2) % 5][w_];                                  \
      const float ym2_ = m[(s) % 5][w_], ym1_ = m[(s + 1) % 5][w_];          \
      const float yp1_ = m[(s + 3) % 5][w_], yp2_ = m[(s + 4) % 5][w_];      \
      const int d1_ = y0_ < ym2_, d2_ = y0_ < ym1_;                          \
      const int d3_ = y0_ <= yp1_, d4_ = y0_ <= yp2_;                        \
      int u_ = (d1_ & d2_) + (d2_ & d3_) + (d3_ & d4_);                      \
      if (w_ < 2) { v_ = lv ? v_ : 0; u_ = lv ? u_ : 0; }                    \
      if (w_ >= 4) { v_ = rv ? v_ : 0; u_ = rv ? u_ : 0; }                   \
      vrM_[w_] = v_;                                                         \
      vrm_[w_] = u_;                                                         \
    }                                                                        \
    const int AP_ = Ap[(s + 2) % 5], am_ = ap[(s + 2) % 5];                  \
    float o_[4];                                                             \
    _Pragma("unroll")                                                        \
    for (int k_ = 0; k_ < 4; ++k_) {                                         \
      int cp_ = 0, cm_ = 0;                                                  \
      _Pragma("unroll")                                                      \
      for (int o2_ = 0; o2_ < 3; ++o2_) {                                    \
        const int wjl_ = k_ + 2 - o2_;                                       \
        if (((AP_ >> (2 * wjl_)) & 3) == o2_) cp_ += vrM_[wjl_];             \
        if (((am_ >> (2 * wjl_)) & 3) == o2_) cm_ += vrm_[wjl_];             \
      }                                                                      \
      o_[k_] = (float)(cp_ - cm_);                                           \
    }                                                                        \
    *(float4*)(op + (r0 + (s)) * WW + c0) =                                  \
        make_float4(o_[0], o_[1], o_[2], o_[3]);                             \
  }

__global__ __launch_bounds__(BLOCK, 4)
void energy_pool2d_kernel(const float* __restrict__ x, float* __restrict__ out) {
  const int tid = threadIdx.x;
  const int ct = tid & 31;       // col-group: output cols [4ct, 4ct+4)
  const int rg = tid >> 5;       // row-group: output rows [16rg, 16rg+16)
  const int c0 = ct * 4;
  const int r0 = rg * 16;
  const float* __restrict__ xp = x + (size_t)blockIdx.x * PLANE;
  float* __restrict__ op = out + (size_t)blockIdx.x * PLANE;

  // Clamped load bases (garbage columns are gated via lv/rv below).
  const int bc0 = (ct == 0) ? 0 : (c0 - 4);
  const int bc2 = (ct == 31) ? 120 : (c0 + 4);
  const bool lv = (ct > 0);   // wj = c0-2, c0-1 exist
  const bool rv = (ct < 31);  // wj = c0+2, c0+3 are <= 125

  // Rolling 5-row h-stat window over 6 wj offsets.
  float M[5][6], m[5][6];
  int Ap[5], ap[5];

  // Prologue: rows r0-2 .. r0+1 into slots 0..3.
  HSTAT(0, r0 - 2)
  HSTAT(1, r0 - 1)
  HSTAT(2, r0)
  HSTAT(3, r0 + 1)

  STEPROW(0)  STEPROW(1)  STEPROW(2)  STEPROW(3)
  STEPROW(4)  STEPROW(5)  STEPROW(6)  STEPROW(7)
  STEPROW(8)  STEPROW(9)  STEPROW(10) STEPROW(11)
  STEPROW(12) STEPROW(13) STEPROW(14) STEPROW(15)
}

extern "C" void kernel_launch(void* const* d_in, const int* in_sizes, int n_in,
                              void* d_out, int out_size, void* d_ws, size_t ws_size,
                              hipStream_t stream) {
  const float* x = (const float*)d_in[0];
  float* out = (float*)d_out;
  energy_pool2d_kernel<<<NPLANES, BLOCK, 0, stream>>>(x, out);
}

// Round 14
// 33.880 us; speedup vs baseline: 1.1957x; 1.1957x over previous
//
#include <hip/hip_runtime.h>

// EnergyPool2d: N=16, C=64, H=W=128, 3x3 windows stride 1 -> Ho=Wo=126.
// +1 at first-argmax flat index, -1 at first-argmin flat index per window.
//
// R14: true write/compute overlap via RAW s_barrier. hipcc drains vmcnt(0)
// at every __syncthreads (the m97 20% stall) — so R10's "fire-and-forget"
// writeout actually drained at the next barrier. Here barriers are
// __builtin_amdgcn_s_barrier() with explicit lgkmcnt(0)-ONLY waits (LDS
// visibility), so global stores of strip s drain under strip s+1's
// compute and at kernel end. Writes use nontemporal stores so 64 MB of
// never-re-read output doesn't evict the L3-resident input.
// Block = 512 thr, two 32-row strips, double-buffered 2x16KB LDS counts,
// R4 tiles + ownership guard (proven exact).

#define WW 128
#define PLANE (128 * 128)
#define SROWS 32
#define SPLANE (SROWS * WW)  // 4096 ints = 16 KB
#define NPLANES (16 * 64)    // 1024
#define BLOCK 512

typedef float vf4 __attribute__((ext_vector_type(4)));

// First-occurrence argmax/argmin over a 3x3 window, row-major scan order
// (strict > / <). Ownership guard: only rows [bias/128, bias/128+32) land.
__device__ __forceinline__ void scan9(float w0, float w1, float w2,
                                      float w3, float w4, float w5,
                                      float w6, float w7, float w8,
                                      int base, int bias, int* __restrict__ cnt) {
    float vmax = w0, vmin = w0;
    int omax = 0, omin = 0;
#define STEP(v, off)                                      \
    do {                                                  \
        if ((v) > vmax) { vmax = (v); omax = (off); }     \
        if ((v) < vmin) { vmin = (v); omin = (off); }     \
    } while (0)
    STEP(w1, 1);
    STEP(w2, 2);
    STEP(w3, WW);
    STEP(w4, WW + 1);
    STEP(w5, WW + 2);
    STEP(w6, 2 * WW);
    STEP(w7, 2 * WW + 1);
    STEP(w8, 2 * WW + 2);
#undef STEP
    const int iM = base + omax - bias;
    if ((unsigned)iM < SPLANE) atomicAdd(&cnt[iM], 1);
    const int im = base + omin - bias;
    if ((unsigned)im < SPLANE) atomicAdd(&cnt[im], -1);
}

__global__ __launch_bounds__(BLOCK, 8)
void energy_pool2d_kernel(const float* __restrict__ x, float* __restrict__ out) {
    __shared__ int cnt[2][SPLANE]; // 32 KB total

    const int tid = threadIdx.x;
    const int plane = blockIdx.x >> 1;
    const int hp = blockIdx.x & 1;   // strip pair: strips {0,1} or {2,3}
    const float* __restrict__ xp = x + (size_t)plane * PLANE;
    float* __restrict__ op = out + (size_t)plane * PLANE;

#pragma unroll
    for (int s = 0; s < 2; ++s) {
        const int q = hp * 2 + s;        // strip index 0..3
        const int R0 = q * SROWS;        // owned plane rows [R0, R0+32)
        const int bias = R0 * WW;
        int* __restrict__ c = &cnt[s][0];

        // Zero this strip's count buffer (1024 int4 / 512 thr).
        int4* cz = (int4*)c;
        cz[tid] = make_int4(0, 0, 0, 0);
        cz[tid + BLOCK] = make_int4(0, 0, 0, 0);
        asm volatile("s_waitcnt lgkmcnt(0)" ::: "memory");
        __builtin_amdgcn_s_barrier();   // NO vmcnt drain: prior strip's
                                        // stores keep flying under compute.

        // Windows whose footprint touches owned rows: top in
        // [R0-2, R0+31] clipped to [0,125]. Even row counts (32 or 34).
        const int wrb = (q == 0) ? 0 : (R0 - 2);
        const int wre = (q == 3) ? 126 : (R0 + SROWS);
        const int ntiles = ((wre - wrb) >> 1) * 32; // 512 or 544

        for (int t = tid; t < ntiles; t += BLOCK) {
            const int rt = t >> 5;
            const int ct = t & 31;
            const int wr0 = wrb + rt * 2;   // window rows wr0, wr0+1 (<=125)
            const int j0 = ct * 4;
            const float* __restrict__ p = xp + wr0 * WW + j0;

            // 4 input rows x 8 cols; right float4 skipped at the right
            // edge (ct=31 -> window cols 124,125 only; loads in-bounds).
            const float4 a0 = *(const float4*)(p);
            const float4 a1 = *(const float4*)(p + WW);
            const float4 a2 = *(const float4*)(p + 2 * WW);
            const float4 a3 = *(const float4*)(p + 3 * WW);
            float4 b0, b1, b2, b3;
            if (ct < 31) {
                b0 = *(const float4*)(p + 4);
                b1 = *(const float4*)(p + WW + 4);
                b2 = *(const float4*)(p + 2 * WW + 4);
                b3 = *(const float4*)(p + 3 * WW + 4);
            } else {
                b0 = b1 = b2 = b3 = make_float4(0.f, 0.f, 0.f, 0.f);
            }
            const float r0[8] = {a0.x, a0.y, a0.z, a0.w, b0.x, b0.y, b0.z, b0.w};
            const float r1[8] = {a1.x, a1.y, a1.z, a1.w, b1.x, b1.y, b1.z, b1.w};
            const float r2[8] = {a2.x, a2.y, a2.z, a2.w, b2.x, b2.y, b2.z, b2.w};
            const float r3[8] = {a3.x, a3.y, a3.z, a3.w, b3.x, b3.y, b3.z, b3.w};

            const int nw = (ct < 31) ? 4 : 2;
            const int base0 = wr0 * WW + j0;
#pragma unroll
            for (int cc = 0; cc < 4; ++cc) {
                if (cc < nw) {
                    scan9(r0[cc], r0[cc + 1], r0[cc + 2],
                          r1[cc], r1[cc + 1], r1[cc + 2],
                          r2[cc], r2[cc + 1], r2[cc + 2], base0 + cc, bias, c);
                    scan9(r1[cc], r1[cc + 1], r1[cc + 2],
                          r2[cc], r2[cc + 1], r2[cc + 2],
                          r3[cc], r3[cc + 1], r3[cc + 2], base0 + WW + cc, bias, c);
                }
            }
        }
        asm volatile("s_waitcnt lgkmcnt(0)" ::: "memory");
        __builtin_amdgcn_s_barrier();   // counts final; again no vmcnt drain.

        // Writeout strip q: nontemporal float4 stores, fire-and-forget.
        const int4* cr = (const int4*)c;
        vf4* __restrict__ o4 = (vf4*)(op + bias);
#pragma unroll
        for (int i = 0; i < 2; ++i) {
            const int4 ci = cr[tid + i * BLOCK];
            vf4 f;
            f.x = (float)ci.x; f.y = (float)ci.y;
            f.z = (float)ci.z; f.w = (float)ci.w;
            __builtin_nontemporal_store(f, o4 + tid + i * BLOCK);
        }
        // No barrier here: next iteration zeroes the OTHER buffer.
    }
}

extern "C" void kernel_launch(void* const* d_in, const int* in_sizes, int n_in,
                              void* d_out, int out_size, void* d_ws, size_t ws_size,
                              hipStream_t stream) {
    const float* x = (const float*)d_in[0];
    float* out = (float*)d_out;
    energy_pool2d_kernel<<<NPLANES * 2, BLOCK, 0, stream>>>(x, out);
}